// Round 11
// baseline (605.204 us; speedup 1.0000x reference)
//
#include <hip/hip_runtime.h>

typedef unsigned short ushort_t;
typedef __attribute__((ext_vector_type(8))) short short8;
typedef __attribute__((ext_vector_type(4))) float f32x4;

#define TOKENS  4096
#define H_DIM   1024
#define HFF_DIM 4096
#define NEXP    8

// round-to-nearest-even f32 -> bf16
__device__ __forceinline__ ushort_t f2b(float f) {
    union { float f; unsigned u; } v; v.f = f;
    unsigned r = v.u + 0x7fffu + ((v.u >> 16) & 1u);
    return (ushort_t)(r >> 16);
}

// jax.nn.gelu default: approximate=True (tanh form)
__device__ __forceinline__ float gelu_tanh(float x) {
    float u = 0.7978845608028654f * (x + 0.044715f * x * x * x);
    return 0.5f * x * (1.0f + tanhf(u));
}

// async global->LDS, 16B per lane; LDS dest is wave-uniform base + lane*16
__device__ __forceinline__ void gload16(const ushort_t* g, ushort_t* l) {
    __builtin_amdgcn_global_load_lds(
        (const __attribute__((address_space(1))) unsigned int*)g,
        (__attribute__((address_space(3))) unsigned int*)l,
        16, 0, 0);
}

// ---------------- routing ----------------
__global__ void route_kernel(const float* __restrict__ probs,
                             const int* __restrict__ idx,
                             int* __restrict__ count,
                             int* __restrict__ token_id,
                             float* __restrict__ gate) {
    int t = blockIdx.x * blockDim.x + threadIdx.x;
    if (t >= TOKENS) return;
    int i0 = idx[t * 2 + 0];
    int i1 = idx[t * 2 + 1];
    float p0 = probs[t * 2 + 0];
    float p1 = probs[t * 2 + 1];
    if (i0 == i1) {
        float p = fmaxf(p0, p1);
        int pos = atomicAdd(&count[i0], 1);
        token_id[i0 * TOKENS + pos] = t;
        gate[i0 * TOKENS + pos] = p;
    } else {
        int pos = atomicAdd(&count[i0], 1);
        token_id[i0 * TOKENS + pos] = t;
        gate[i0 * TOKENS + pos] = p0;
        pos = atomicAdd(&count[i1], 1);
        token_id[i1 * TOKENS + pos] = t;
        gate[i1 * TOKENS + pos] = p1;
    }
}

__global__ void prefix_kernel(const int* __restrict__ count, int* __restrict__ offsets) {
    if (threadIdx.x == 0 && blockIdx.x == 0) {
        int acc = 0;
        for (int e = 0; e < NEXP; ++e) { offsets[e] = acc; acc += count[e]; }
        offsets[NEXP] = acc;
    }
}

// ---------------- f32 -> bf16 bulk convert (memory-bound) ----------------
__global__ void cvt_kernel(const float* __restrict__ src, ushort_t* __restrict__ dst, int n8) {
    int i = blockIdx.x * blockDim.x + threadIdx.x;
    if (i >= n8) return;
    const float4* s = (const float4*)(src + (size_t)i * 8);
    float4 a = s[0], b = s[1];
    ushort_t o[8];
    o[0] = f2b(a.x); o[1] = f2b(a.y); o[2] = f2b(a.z); o[3] = f2b(a.w);
    o[4] = f2b(b.x); o[5] = f2b(b.y); o[6] = f2b(b.z); o[7] = f2b(b.w);
    *(short8*)(dst + (size_t)i * 8) = *(short8*)o;
}

// BK=64 staging with 16B-granule XOR swizzle (rule #21 compliant):
// LDS dest stays linear (gload16 requirement); the per-lane GLOBAL source
// column is inverse-swizzled; ds_read applies the same XOR. Row stride is
// 128B so unswizzled reads would 32-way conflict; granule g^(row&7) spreads
// 64 lanes uniformly (8/bank-slot = b128 optimum).
// Rationale: gemm2 latency-bound (MfmaUtil 21.6%, occ 19%, FETCH tiny after
// T1 swizzle) -> halve the count of serial barrier/load exposures (BK 32->64).

// ---------------- GEMM1: h[row] = gelu(xb[tok] . W1b[e]^T), bf16 out ----------------
__global__ __launch_bounds__(256) void gemm1_kernel(
        const ushort_t* __restrict__ xb, const ushort_t* __restrict__ W1b,
        const int* __restrict__ count, const int* __restrict__ offsets,
        const int* __restrict__ token_id, ushort_t* __restrict__ h) {
    const int wg  = blockIdx.x;
    const int swz = (wg & 7) * (NEXP * 32 * 32 / 8) + (wg >> 3);
    const int e   = swz >> 10;          // 32 mt * 32 nt = 1024 per expert
    const int rem = swz & 1023;
    const int mt  = rem >> 5;           // nt fastest: A-panel sharers consecutive
    const int nt  = rem & 31;

    const int cnt = count[e];
    if (mt * 128 >= cnt) return;
    const int base = offsets[e];

    __shared__ __align__(16) ushort_t As[128 * 64];
    __shared__ __align__(16) ushort_t Bs[128 * 64];

    const int tid = threadIdx.x;
    const int lane = tid & 63;
    const int wave = tid >> 6;

    // staging: wave w stages rows [w*32, w*32+32) in 4 gloads of 8 rows each.
    // lane l -> row chunk+ (l>>3), LDS granule (l&7); source col granule
    // (l&7) ^ (l>>3)  (inverse swizzle; row&7 == (l>>3) for all chunks).
    const int srow = (lane >> 3);
    const int sxc  = (((lane & 7) ^ srow) << 3);   // source col in ushorts

    int tok_[4];
#pragma unroll
    for (int j = 0; j < 4; ++j) {
        int ra = mt * 128 + (wave << 5) + j * 8 + srow;
        if (ra >= cnt) ra = cnt - 1;               // clamp: garbage rows unused
        tok_[j] = token_id[e * TOKENS + ra];
    }
    const ushort_t* pa[4];
    const ushort_t* pb[4];
#pragma unroll
    for (int j = 0; j < 4; ++j) {
        pa[j] = xb + (size_t)tok_[j] * H_DIM + sxc;
        pb[j] = W1b + (size_t)e * HFF_DIM * H_DIM
                + (size_t)(nt * 128 + (wave << 5) + j * 8 + srow) * H_DIM + sxc;
    }

    const int wm = (wave >> 1) << 6;
    const int wn = (wave & 1) << 6;
    const int lr = lane & 15;
    const int lq = lane >> 4;
    const int l7 = lane & 7;                       // == row&7 for fragment rows

    f32x4 acc[4][4];
#pragma unroll
    for (int mi = 0; mi < 4; ++mi)
#pragma unroll
        for (int ni = 0; ni < 4; ++ni)
            acc[mi][ni] = (f32x4){0.f, 0.f, 0.f, 0.f};

    for (int k0 = 0; k0 < H_DIM; k0 += 64) {
        __syncthreads();                 // prior ds_reads done before overwrite
#pragma unroll
        for (int j = 0; j < 4; ++j) {
            gload16(pa[j] + k0, &As[((wave << 5) + j * 8) * 64]);
            gload16(pb[j] + k0, &Bs[((wave << 5) + j * 8) * 64]);
        }
        __syncthreads();                 // loads landed (vmcnt drained at barrier)

#pragma unroll
        for (int ks = 0; ks < 2; ++ks) {
            short8 af[4], bf[4];
#pragma unroll
            for (int mi = 0; mi < 4; ++mi)
                af[mi] = *(const short8*)&As[(wm + mi * 16 + lr) * 64
                                             + ((((ks << 2) | lq) ^ l7) << 3)];
#pragma unroll
            for (int ni = 0; ni < 4; ++ni)
                bf[ni] = *(const short8*)&Bs[(wn + ni * 16 + lr) * 64
                                             + ((((ks << 2) | lq) ^ l7) << 3)];
#pragma unroll
            for (int mi = 0; mi < 4; ++mi)
#pragma unroll
                for (int ni = 0; ni < 4; ++ni)
                    acc[mi][ni] = __builtin_amdgcn_mfma_f32_16x16x32_bf16(
                        af[mi], bf[ni], acc[mi][ni], 0, 0, 0);
        }
    }

    // epilogue: gelu -> bf16 h
#pragma unroll
    for (int mi = 0; mi < 4; ++mi) {
#pragma unroll
        for (int r = 0; r < 4; ++r) {
            int m = mt * 128 + wm + mi * 16 + lq * 4 + r;
            if (m < cnt) {
                ushort_t* hp = h + (size_t)(base + m) * HFF_DIM + nt * 128 + wn + lr;
#pragma unroll
                for (int ni = 0; ni < 4; ++ni)
                    hp[ni * 16] = f2b(gelu_tanh(acc[mi][ni][r]));
            }
        }
    }
}

// ---------------- GEMM2: out[tok] += gate * (h[row] . W2b[e]^T) ----------------
__global__ __launch_bounds__(256) void gemm2_kernel(
        const ushort_t* __restrict__ h, const ushort_t* __restrict__ W2b,
        const int* __restrict__ count, const int* __restrict__ offsets,
        const int* __restrict__ token_id, const float* __restrict__ gate,
        float* __restrict__ out) {
    const int wg  = blockIdx.x;
    const int swz = (wg & 7) * (NEXP * 32 * 8 / 8) + (wg >> 3);
    const int e   = swz >> 8;           // 32 mt * 8 nt = 256 per expert
    const int rem = swz & 255;
    const int mt  = rem >> 3;
    const int nt  = rem & 7;

    const int cnt = count[e];
    if (mt * 128 >= cnt) return;
    const int base = offsets[e];

    __shared__ __align__(16) ushort_t As[128 * 64];
    __shared__ __align__(16) ushort_t Bs[128 * 64];

    const int tid = threadIdx.x;
    const int lane = tid & 63;
    const int wave = tid >> 6;

    const int srow = (lane >> 3);
    const int sxc  = (((lane & 7) ^ srow) << 3);

    const ushort_t* pa[4];
    const ushort_t* pb[4];
#pragma unroll
    for (int j = 0; j < 4; ++j) {
        int ra = mt * 128 + (wave << 5) + j * 8 + srow;
        if (ra >= cnt) ra = cnt - 1;
        pa[j] = h + (size_t)(base + ra) * HFF_DIM + sxc;
        pb[j] = W2b + (size_t)e * H_DIM * HFF_DIM
                + (size_t)(nt * 128 + (wave << 5) + j * 8 + srow) * HFF_DIM + sxc;
    }

    const int wm = (wave >> 1) << 6;
    const int wn = (wave & 1) << 6;
    const int lr = lane & 15;
    const int lq = lane >> 4;
    const int l7 = lane & 7;

    f32x4 acc[4][4];
#pragma unroll
    for (int mi = 0; mi < 4; ++mi)
#pragma unroll
        for (int ni = 0; ni < 4; ++ni)
            acc[mi][ni] = (f32x4){0.f, 0.f, 0.f, 0.f};

    for (int k0 = 0; k0 < HFF_DIM; k0 += 64) {
        __syncthreads();
#pragma unroll
        for (int j = 0; j < 4; ++j) {
            gload16(pa[j] + k0, &As[((wave << 5) + j * 8) * 64]);
            gload16(pb[j] + k0, &Bs[((wave << 5) + j * 8) * 64]);
        }
        __syncthreads();

#pragma unroll
        for (int ks = 0; ks < 2; ++ks) {
            short8 af[4], bf[4];
#pragma unroll
            for (int mi = 0; mi < 4; ++mi)
                af[mi] = *(const short8*)&As[(wm + mi * 16 + lr) * 64
                                             + ((((ks << 2) | lq) ^ l7) << 3)];
#pragma unroll
            for (int ni = 0; ni < 4; ++ni)
                bf[ni] = *(const short8*)&Bs[(wn + ni * 16 + lr) * 64
                                             + ((((ks << 2) | lq) ^ l7) << 3)];
#pragma unroll
            for (int mi = 0; mi < 4; ++mi)
#pragma unroll
                for (int ni = 0; ni < 4; ++ni)
                    acc[mi][ni] = __builtin_amdgcn_mfma_f32_16x16x32_bf16(
                        af[mi], bf[ni], acc[mi][ni], 0, 0, 0);
        }
    }

    // epilogue: scale by gate, scatter-add into out
#pragma unroll
    for (int mi = 0; mi < 4; ++mi) {
#pragma unroll
        for (int r = 0; r < 4; ++r) {
            int m = mt * 128 + wm + mi * 16 + lq * 4 + r;
            if (m < cnt) {
                int tok = token_id[e * TOKENS + m];
                float g = gate[e * TOKENS + m];
                float* op = out + (size_t)tok * H_DIM + nt * 128 + wn + lr;
#pragma unroll
                for (int ni = 0; ni < 4; ++ni)
                    atomicAdd(&op[ni * 16], g * acc[mi][ni][r]);
            }
        }
    }
}

extern "C" void kernel_launch(void* const* d_in, const int* in_sizes, int n_in,
                              void* d_out, int out_size, void* d_ws, size_t ws_size,
                              hipStream_t stream) {
    const float* x     = (const float*)d_in[0];
    const float* probs = (const float*)d_in[1];
    const int*   idx   = (const int*)d_in[2];
    const float* W1    = (const float*)d_in[3];
    const float* W2    = (const float*)d_in[4];
    float* out = (float*)d_out;

    char* ws = (char*)d_ws;
    int*      count    = (int*)ws;                               // 8 ints
    int*      offsets  = (int*)(ws + 64);                        // 9 ints
    int*      token_id = (int*)(ws + 4096);                      // 8*4096 ints (128 KB)
    float*    gate     = (float*)(ws + 4096 + 8 * TOKENS * 4);   // 128 KB
    ushort_t* xb       = (ushort_t*)(ws + ((size_t)1 << 20));              // 8 MB bf16 x
    ushort_t* Wb       = (ushort_t*)(ws + ((size_t)1 << 20) + ((size_t)8 << 20));   // 64 MB (W1b then W2b)
    ushort_t* h        = (ushort_t*)(ws + ((size_t)1 << 20) + ((size_t)72 << 20));  // 64 MB
    // total workspace footprint ~137 MB

    hipMemsetAsync(count, 0, 64, stream);
    hipMemsetAsync(out, 0, (size_t)out_size * sizeof(float), stream);

    route_kernel<<<TOKENS / 256, 256, 0, stream>>>(probs, idx, count, token_id, gate);
    prefix_kernel<<<1, 64, 0, stream>>>(count, offsets);

    // bf16 pre-conversion (once per launch, memory-bound)
    {
        int n8 = TOKENS * H_DIM / 8;
        cvt_kernel<<<(n8 + 255) / 256, 256, 0, stream>>>(x, xb, n8);
    }
    {
        int n8 = NEXP * HFF_DIM * H_DIM / 8;
        cvt_kernel<<<(n8 + 255) / 256, 256, 0, stream>>>(W1, Wb, n8);
    }

    gemm1_kernel<<<NEXP * 32 * 32, 256, 0, stream>>>(xb, Wb, count, offsets, token_id, h);

    // convert W2 into the same buffer (stream-ordered after gemm1 reads W1b)
    {
        int n8 = NEXP * H_DIM * HFF_DIM / 8;
        cvt_kernel<<<(n8 + 255) / 256, 256, 0, stream>>>(W2, Wb, n8);
    }

    gemm2_kernel<<<NEXP * 32 * 8, 256, 0, stream>>>(h, Wb, count, offsets, token_id, gate, out);
}

// Round 13
// 536.804 us; speedup vs baseline: 1.1274x; 1.1274x over previous
//
#include <hip/hip_runtime.h>

typedef unsigned short ushort_t;
typedef __attribute__((ext_vector_type(8))) short short8;
typedef __attribute__((ext_vector_type(4))) float f32x4;

#define TOKENS  4096
#define H_DIM   1024
#define HFF_DIM 4096
#define NEXP    8

// round-to-nearest-even f32 -> bf16
__device__ __forceinline__ ushort_t f2b(float f) {
    union { float f; unsigned u; } v; v.f = f;
    unsigned r = v.u + 0x7fffu + ((v.u >> 16) & 1u);
    return (ushort_t)(r >> 16);
}

// jax.nn.gelu default: approximate=True (tanh form)
__device__ __forceinline__ float gelu_tanh(float x) {
    float u = 0.7978845608028654f * (x + 0.044715f * x * x * x);
    return 0.5f * x * (1.0f + tanhf(u));
}

// async global->LDS, 16B per lane; LDS dest is wave-uniform base + lane*16
__device__ __forceinline__ void gload16(const ushort_t* g, ushort_t* l) {
    __builtin_amdgcn_global_load_lds(
        (const __attribute__((address_space(1))) unsigned int*)g,
        (__attribute__((address_space(3))) unsigned int*)l,
        16, 0, 0);
}

// ---------------- fused x-cvt + routing ----------------
// grid = 2048 blocks x 256: every thread converts 8 floats of x;
// first 16 blocks (4096 threads) also route. Route atomics are
// wave-aggregated (G12): ballot per (slot,expert) -> <=16 atomics/wave
// instead of 128 serialized RMWs on 8 hot counters.
__global__ void route_cvt_kernel(const float* __restrict__ probs,
                                 const int* __restrict__ idx,
                                 const float* __restrict__ x,
                                 ushort_t* __restrict__ xb,
                                 int* __restrict__ count,
                                 int* __restrict__ token_id,
                                 float* __restrict__ gate) {
    const int gid = blockIdx.x * blockDim.x + threadIdx.x;

    // x conversion: 8 floats per thread (grid exactly covers TOKENS*H_DIM/8)
    {
        const float4* s = (const float4*)(x + (size_t)gid * 8);
        float4 a = s[0], b = s[1];
        ushort_t o[8];
        o[0] = f2b(a.x); o[1] = f2b(a.y); o[2] = f2b(a.z); o[3] = f2b(a.w);
        o[4] = f2b(b.x); o[5] = f2b(b.y); o[6] = f2b(b.z); o[7] = f2b(b.w);
        *(short8*)(xb + (size_t)gid * 8) = *(short8*)o;
    }

    if (blockIdx.x >= TOKENS / 256) return;   // only first 16 blocks route (full waves)
    const int t = gid;                        // < TOKENS
    const int lane = threadIdx.x & 63;

    const int i0 = idx[t * 2 + 0];
    const int i1 = idx[t * 2 + 1];
    const float p0 = probs[t * 2 + 0];
    const float p1 = probs[t * 2 + 1];
    const bool dup = (i0 == i1);
    const float q0 = dup ? fmaxf(p0, p1) : p0;

#pragma unroll
    for (int k = 0; k < 2; ++k) {
        const int want = (k == 0) ? i0 : (dup ? -1 : i1);
        const float p  = (k == 0) ? q0 : p1;
#pragma unroll
        for (int e = 0; e < NEXP; ++e) {
            unsigned long long m = __ballot(want == e);
            if (m == 0ull) continue;                       // wave-uniform
            if (want == e) {
                const int lead = __ffsll((long long)m) - 1;
                int base = 0;
                if (lane == lead) base = atomicAdd(&count[e], (int)__popcll(m));
                base = __shfl(base, lead);
                const int pos = base + (int)__popcll(m & ((1ull << lane) - 1ull));
                token_id[e * TOKENS + pos] = t;
                gate[e * TOKENS + pos] = p;
            }
        }
    }
}

// ---------------- f32 -> bf16 bulk convert (weights; memory-bound) ----------------
__global__ void cvt_kernel(const float* __restrict__ src, ushort_t* __restrict__ dst, int n8) {
    int i = blockIdx.x * blockDim.x + threadIdx.x;
    if (i >= n8) return;
    const float4* s = (const float4*)(src + (size_t)i * 8);
    float4 a = s[0], b = s[1];
    ushort_t o[8];
    o[0] = f2b(a.x); o[1] = f2b(a.y); o[2] = f2b(a.z); o[3] = f2b(a.w);
    o[4] = f2b(b.x); o[5] = f2b(b.y); o[6] = f2b(b.z); o[7] = f2b(b.w);
    *(short8*)(dst + (size_t)i * 8) = *(short8*)o;
}

// ---------------- GEMM1: h[row] = gelu(xb[tok] . W1b[e]^T), bf16 out ----------------
// R8-verified structure: m97 128x128 tile, BK=32, 4 waves, gload_lds width-16,
// 1D grid + XCD-chunked swizzle (T1). Per-expert base computed inline
// (prefix over count[0..e), 8 scalar loads) -- prefix_kernel launch dropped.
__global__ __launch_bounds__(256) void gemm1_kernel(
        const ushort_t* __restrict__ xb, const ushort_t* __restrict__ W1b,
        const int* __restrict__ count, const int* __restrict__ token_id,
        ushort_t* __restrict__ h) {
    const int wg  = blockIdx.x;
    const int swz = (wg & 7) * (NEXP * 32 * 32 / 8) + (wg >> 3);
    const int e   = swz >> 10;          // 32 mt * 32 nt = 1024 per expert
    const int rem = swz & 1023;
    const int mt  = rem >> 5;           // nt fastest: A-panel sharers consecutive
    const int nt  = rem & 31;

    const int cnt = count[e];
    if (mt * 128 >= cnt) return;
    int base = 0;
    for (int i = 0; i < e; ++i) base += count[i];

    __shared__ __align__(16) ushort_t As[128 * 32];
    __shared__ __align__(16) ushort_t Bs[128 * 32];

    const int tid = threadIdx.x;
    const int lane = tid & 63;
    const int wave = tid >> 6;

    // staging geometry: wave w stages rows [w*32, w*32+32), 2 loads of 16 rows.
    const int sr0 = (wave << 5) + (lane >> 2);
    const int sr1 = sr0 + 16;
    const int sc  = (lane & 3) << 3;

    int ra0 = mt * 128 + sr0; if (ra0 >= cnt) ra0 = cnt - 1;   // clamp: garbage rows unused
    int ra1 = mt * 128 + sr1; if (ra1 >= cnt) ra1 = cnt - 1;
    const int t0 = token_id[e * TOKENS + ra0];
    const int t1 = token_id[e * TOKENS + ra1];
    const ushort_t* pa0 = xb + (size_t)t0 * H_DIM + sc;
    const ushort_t* pa1 = xb + (size_t)t1 * H_DIM + sc;
    const ushort_t* pb0 = W1b + (size_t)e * HFF_DIM * H_DIM
                          + (size_t)(nt * 128 + sr0) * H_DIM + sc;
    const ushort_t* pb1 = pb0 + (size_t)16 * H_DIM;
    ushort_t* lA0 = &As[wave << 10];
    ushort_t* lA1 = lA0 + 512;
    ushort_t* lB0 = &Bs[wave << 10];
    ushort_t* lB1 = lB0 + 512;

    const int wm = (wave >> 1) << 6;
    const int wn = (wave & 1) << 6;
    const int lr = lane & 15;
    const int lq = lane >> 4;

    f32x4 acc[4][4];
#pragma unroll
    for (int mi = 0; mi < 4; ++mi)
#pragma unroll
        for (int ni = 0; ni < 4; ++ni)
            acc[mi][ni] = (f32x4){0.f, 0.f, 0.f, 0.f};

    for (int k0 = 0; k0 < H_DIM; k0 += 32) {
        __syncthreads();                 // prior ds_reads done before overwrite
        gload16(pa0 + k0, lA0);
        gload16(pa1 + k0, lA1);
        gload16(pb0 + k0, lB0);
        gload16(pb1 + k0, lB1);
        __syncthreads();                 // loads landed (vmcnt drained at barrier)

        short8 af[4], bf[4];
#pragma unroll
        for (int mi = 0; mi < 4; ++mi)
            af[mi] = *(const short8*)&As[(wm + mi * 16 + lr) * 32 + lq * 8];
#pragma unroll
        for (int ni = 0; ni < 4; ++ni)
            bf[ni] = *(const short8*)&Bs[(wn + ni * 16 + lr) * 32 + lq * 8];
#pragma unroll
        for (int mi = 0; mi < 4; ++mi)
#pragma unroll
            for (int ni = 0; ni < 4; ++ni)
                acc[mi][ni] = __builtin_amdgcn_mfma_f32_16x16x32_bf16(
                    af[mi], bf[ni], acc[mi][ni], 0, 0, 0);
    }

    // epilogue: gelu -> bf16 h
#pragma unroll
    for (int mi = 0; mi < 4; ++mi) {
#pragma unroll
        for (int r = 0; r < 4; ++r) {
            int m = mt * 128 + wm + mi * 16 + lq * 4 + r;
            if (m < cnt) {
                ushort_t* hp = h + (size_t)(base + m) * HFF_DIM + nt * 128 + wn + lr;
#pragma unroll
                for (int ni = 0; ni < 4; ++ni)
                    hp[ni * 16] = f2b(gelu_tanh(acc[mi][ni][r]));
            }
        }
    }
}

// ---------------- GEMM2: out[tok] += gate * (h[row] . W2b[e]^T) ----------------
__global__ __launch_bounds__(256) void gemm2_kernel(
        const ushort_t* __restrict__ h, const ushort_t* __restrict__ W2b,
        const int* __restrict__ count, const int* __restrict__ token_id,
        const float* __restrict__ gate, float* __restrict__ out) {
    const int wg  = blockIdx.x;
    const int swz = (wg & 7) * (NEXP * 32 * 8 / 8) + (wg >> 3);
    const int e   = swz >> 8;           // 32 mt * 8 nt = 256 per expert
    const int rem = swz & 255;
    const int mt  = rem >> 3;
    const int nt  = rem & 7;

    const int cnt = count[e];
    if (mt * 128 >= cnt) return;
    int base = 0;
    for (int i = 0; i < e; ++i) base += count[i];

    __shared__ __align__(16) ushort_t As[128 * 32];
    __shared__ __align__(16) ushort_t Bs[128 * 32];

    const int tid = threadIdx.x;
    const int lane = tid & 63;
    const int wave = tid >> 6;

    const int sr0 = (wave << 5) + (lane >> 2);
    const int sr1 = sr0 + 16;
    const int sc  = (lane & 3) << 3;

    int ra0 = mt * 128 + sr0; if (ra0 >= cnt) ra0 = cnt - 1;
    int ra1 = mt * 128 + sr1; if (ra1 >= cnt) ra1 = cnt - 1;
    const ushort_t* pa0 = h + (size_t)(base + ra0) * HFF_DIM + sc;
    const ushort_t* pa1 = h + (size_t)(base + ra1) * HFF_DIM + sc;
    const ushort_t* pb0 = W2b + (size_t)e * H_DIM * HFF_DIM
                          + (size_t)(nt * 128 + sr0) * HFF_DIM + sc;
    const ushort_t* pb1 = pb0 + (size_t)16 * HFF_DIM;
    ushort_t* lA0 = &As[wave << 10];
    ushort_t* lA1 = lA0 + 512;
    ushort_t* lB0 = &Bs[wave << 10];
    ushort_t* lB1 = lB0 + 512;

    const int wm = (wave >> 1) << 6;
    const int wn = (wave & 1) << 6;
    const int lr = lane & 15;
    const int lq = lane >> 4;

    f32x4 acc[4][4];
#pragma unroll
    for (int mi = 0; mi < 4; ++mi)
#pragma unroll
        for (int ni = 0; ni < 4; ++ni)
            acc[mi][ni] = (f32x4){0.f, 0.f, 0.f, 0.f};

    for (int k0 = 0; k0 < HFF_DIM; k0 += 32) {
        __syncthreads();
        gload16(pa0 + k0, lA0);
        gload16(pa1 + k0, lA1);
        gload16(pb0 + k0, lB0);
        gload16(pb1 + k0, lB1);
        __syncthreads();

        short8 af[4], bf[4];
#pragma unroll
        for (int mi = 0; mi < 4; ++mi)
            af[mi] = *(const short8*)&As[(wm + mi * 16 + lr) * 32 + lq * 8];
#pragma unroll
        for (int ni = 0; ni < 4; ++ni)
            bf[ni] = *(const short8*)&Bs[(wn + ni * 16 + lr) * 32 + lq * 8];
#pragma unroll
        for (int mi = 0; mi < 4; ++mi)
#pragma unroll
            for (int ni = 0; ni < 4; ++ni)
                acc[mi][ni] = __builtin_amdgcn_mfma_f32_16x16x32_bf16(
                    af[mi], bf[ni], acc[mi][ni], 0, 0, 0);
    }

    // epilogue: scale by gate, scatter-add into out
#pragma unroll
    for (int mi = 0; mi < 4; ++mi) {
#pragma unroll
        for (int r = 0; r < 4; ++r) {
            int m = mt * 128 + wm + mi * 16 + lq * 4 + r;
            if (m < cnt) {
                int tok = token_id[e * TOKENS + m];
                float g = gate[e * TOKENS + m];
                float* op = out + (size_t)tok * H_DIM + nt * 128 + wn + lr;
#pragma unroll
                for (int ni = 0; ni < 4; ++ni)
                    atomicAdd(&op[ni * 16], g * acc[mi][ni][r]);
            }
        }
    }
}

extern "C" void kernel_launch(void* const* d_in, const int* in_sizes, int n_in,
                              void* d_out, int out_size, void* d_ws, size_t ws_size,
                              hipStream_t stream) {
    const float* x     = (const float*)d_in[0];
    const float* probs = (const float*)d_in[1];
    const int*   idx   = (const int*)d_in[2];
    const float* W1    = (const float*)d_in[3];
    const float* W2    = (const float*)d_in[4];
    float* out = (float*)d_out;

    char* ws = (char*)d_ws;
    int*      count    = (int*)ws;                               // 8 ints
    int*      token_id = (int*)(ws + 4096);                      // 8*4096 ints (128 KB)
    float*    gate     = (float*)(ws + 4096 + 8 * TOKENS * 4);   // 128 KB
    ushort_t* xb       = (ushort_t*)(ws + ((size_t)1 << 20));              // 8 MB bf16 x
    ushort_t* Wb       = (ushort_t*)(ws + ((size_t)1 << 20) + ((size_t)8 << 20));   // 64 MB (W1b then W2b)
    ushort_t* h        = (ushort_t*)(ws + ((size_t)1 << 20) + ((size_t)72 << 20));  // 64 MB
    // total workspace footprint ~137 MB

    hipMemsetAsync(count, 0, 64, stream);
    hipMemsetAsync(out, 0, (size_t)out_size * sizeof(float), stream);

    // fused x-cvt + wave-aggregated routing (one launch)
    route_cvt_kernel<<<TOKENS * H_DIM / 8 / 256, 256, 0, stream>>>(
        probs, idx, x, xb, count, token_id, gate);

    {
        int n8 = NEXP * HFF_DIM * H_DIM / 8;
        cvt_kernel<<<(n8 + 255) / 256, 256, 0, stream>>>(W1, Wb, n8);
    }

    gemm1_kernel<<<NEXP * 32 * 32, 256, 0, stream>>>(xb, Wb, count, token_id, h);

    // convert W2 into the same buffer (stream-ordered after gemm1 reads W1b)
    {
        int n8 = NEXP * H_DIM * HFF_DIM / 8;
        cvt_kernel<<<(n8 + 255) / 256, 256, 0, stream>>>(W2, Wb, n8);
    }

    gemm2_kernel<<<NEXP * 32 * 8, 256, 0, stream>>>(h, Wb, count, token_id, gate, out);
}

// Round 15
// 535.222 us; speedup vs baseline: 1.1308x; 1.0030x over previous
//
#include <hip/hip_runtime.h>

typedef unsigned short ushort_t;
typedef __attribute__((ext_vector_type(8))) short short8;
typedef __attribute__((ext_vector_type(4))) float f32x4;

#define TOKENS  4096
#define H_DIM   1024
#define HFF_DIM 4096
#define NEXP    8

#define XCVT_BLOCKS  (TOKENS * H_DIM / 8 / 256)          // 2048
#define W1CVT_BLOCKS (NEXP * HFF_DIM * H_DIM / 8 / 256)  // 16384
#define W2CVT_BLOCKS (NEXP * H_DIM * HFF_DIM / 8 / 256)  // 16384
#define G1_BLOCKS    (NEXP * 32 * 32)                    // 8192
#define G2_BLOCKS    (NEXP * 32 * 8)                     // 2048

// round-to-nearest-even f32 -> bf16
__device__ __forceinline__ ushort_t f2b(float f) {
    union { float f; unsigned u; } v; v.f = f;
    unsigned r = v.u + 0x7fffu + ((v.u >> 16) & 1u);
    return (ushort_t)(r >> 16);
}

__device__ __forceinline__ void cvt8(const float* __restrict__ src,
                                     ushort_t* __restrict__ dst, size_t i) {
    const float4* s = (const float4*)(src + i * 8);
    float4 a = s[0], b = s[1];
    ushort_t o[8];
    o[0] = f2b(a.x); o[1] = f2b(a.y); o[2] = f2b(a.z); o[3] = f2b(a.w);
    o[4] = f2b(b.x); o[5] = f2b(b.y); o[6] = f2b(b.z); o[7] = f2b(b.w);
    *(short8*)(dst + i * 8) = *(short8*)o;
}

// jax.nn.gelu default: approximate=True (tanh form)
__device__ __forceinline__ float gelu_tanh(float x) {
    float u = 0.7978845608028654f * (x + 0.044715f * x * x * x);
    return 0.5f * x * (1.0f + tanhf(u));
}

// async global->LDS, 16B per lane; LDS dest is wave-uniform base + lane*16
__device__ __forceinline__ void gload16(const ushort_t* g, ushort_t* l) {
    __builtin_amdgcn_global_load_lds(
        (const __attribute__((address_space(1))) unsigned int*)g,
        (__attribute__((address_space(3))) unsigned int*)l,
        16, 0, 0);
}

// ---------------- prep: x-cvt + routing + W1-cvt in ONE launch ----------------
// blocks [0, 2048): x conversion (first 16 also route, wave-aggregated atomics)
// blocks [2048, 18432): W1 conversion. All BW-bound -> packs to ~45 us.
__global__ void prep_kernel(const float* __restrict__ probs,
                            const int* __restrict__ idx,
                            const float* __restrict__ x,
                            ushort_t* __restrict__ xb,
                            const float* __restrict__ W1,
                            ushort_t* __restrict__ W1b,
                            int* __restrict__ count,
                            int* __restrict__ token_id,
                            float* __restrict__ gate) {
    const int wg = blockIdx.x;
    if (wg >= XCVT_BLOCKS) {
        cvt8(W1, W1b, (size_t)(wg - XCVT_BLOCKS) * 256 + threadIdx.x);
        return;
    }
    const int gid = wg * 256 + threadIdx.x;
    cvt8(x, xb, (size_t)gid);

    if (wg >= TOKENS / 256) return;           // only first 16 blocks route (full waves)
    const int t = gid;                        // < TOKENS
    const int lane = threadIdx.x & 63;

    const int i0 = idx[t * 2 + 0];
    const int i1 = idx[t * 2 + 1];
    const float p0 = probs[t * 2 + 0];
    const float p1 = probs[t * 2 + 1];
    const bool dup = (i0 == i1);
    const float q0 = dup ? fmaxf(p0, p1) : p0;

#pragma unroll
    for (int k = 0; k < 2; ++k) {
        const int want = (k == 0) ? i0 : (dup ? -1 : i1);
        const float p  = (k == 0) ? q0 : p1;
#pragma unroll
        for (int e = 0; e < NEXP; ++e) {
            unsigned long long m = __ballot(want == e);
            if (m == 0ull) continue;                       // wave-uniform
            if (want == e) {
                const int lead = __ffsll((long long)m) - 1;
                int base = 0;
                if (lane == lead) base = atomicAdd(&count[e], (int)__popcll(m));
                base = __shfl(base, lead);
                const int pos = base + (int)__popcll(m & ((1ull << lane) - 1ull));
                token_id[e * TOKENS + pos] = t;
                gate[e * TOKENS + pos] = p;
            }
        }
    }
}

// ---------------- f32 -> bf16 bulk convert (fallback path only) ----------------
__global__ void cvt_kernel(const float* __restrict__ src, ushort_t* __restrict__ dst, int n8) {
    int i = blockIdx.x * blockDim.x + threadIdx.x;
    if (i >= n8) return;
    cvt8(src, dst, (size_t)i);
}

// ---------------- GEMM1 (+W2-cvt filler blocks): ----------------
// gemm1 body = R8/R13-verified m97 structure, UNTOUCHED. Blocks >= G1_BLOCKS
// convert W2 -> W2b, filling the ~80% CU capacity gemm1 leaves idle
// (gemm1 is latency-bound: occ 19%, HBM 9%). gemm1 blocks come FIRST so the
// ~512 heavy blocks grab CUs before the cvt flood.
__global__ __launch_bounds__(256) void gemm1_kernel(
        const ushort_t* __restrict__ xb, const ushort_t* __restrict__ W1b,
        const int* __restrict__ count, const int* __restrict__ token_id,
        ushort_t* __restrict__ h,
        const float* __restrict__ W2, ushort_t* __restrict__ W2b) {
    if (blockIdx.x >= G1_BLOCKS) {
        cvt8(W2, W2b, (size_t)(blockIdx.x - G1_BLOCKS) * 256 + threadIdx.x);
        return;
    }
    const int wg  = blockIdx.x;
    const int swz = (wg & 7) * (G1_BLOCKS / 8) + (wg >> 3);
    const int e   = swz >> 10;          // 32 mt * 32 nt = 1024 per expert
    const int rem = swz & 1023;
    const int mt  = rem >> 5;           // nt fastest: A-panel sharers consecutive
    const int nt  = rem & 31;

    const int cnt = count[e];
    if (mt * 128 >= cnt) return;
    int base = 0;
    for (int i = 0; i < e; ++i) base += count[i];

    __shared__ __align__(16) ushort_t As[128 * 32];
    __shared__ __align__(16) ushort_t Bs[128 * 32];

    const int tid = threadIdx.x;
    const int lane = tid & 63;
    const int wave = tid >> 6;

    // staging geometry: wave w stages rows [w*32, w*32+32), 2 loads of 16 rows.
    const int sr0 = (wave << 5) + (lane >> 2);
    const int sr1 = sr0 + 16;
    const int sc  = (lane & 3) << 3;

    int ra0 = mt * 128 + sr0; if (ra0 >= cnt) ra0 = cnt - 1;   // clamp: garbage rows unused
    int ra1 = mt * 128 + sr1; if (ra1 >= cnt) ra1 = cnt - 1;
    const int t0 = token_id[e * TOKENS + ra0];
    const int t1 = token_id[e * TOKENS + ra1];
    const ushort_t* pa0 = xb + (size_t)t0 * H_DIM + sc;
    const ushort_t* pa1 = xb + (size_t)t1 * H_DIM + sc;
    const ushort_t* pb0 = W1b + (size_t)e * HFF_DIM * H_DIM
                          + (size_t)(nt * 128 + sr0) * H_DIM + sc;
    const ushort_t* pb1 = pb0 + (size_t)16 * H_DIM;
    ushort_t* lA0 = &As[wave << 10];
    ushort_t* lA1 = lA0 + 512;
    ushort_t* lB0 = &Bs[wave << 10];
    ushort_t* lB1 = lB0 + 512;

    const int wm = (wave >> 1) << 6;
    const int wn = (wave & 1) << 6;
    const int lr = lane & 15;
    const int lq = lane >> 4;

    f32x4 acc[4][4];
#pragma unroll
    for (int mi = 0; mi < 4; ++mi)
#pragma unroll
        for (int ni = 0; ni < 4; ++ni)
            acc[mi][ni] = (f32x4){0.f, 0.f, 0.f, 0.f};

    for (int k0 = 0; k0 < H_DIM; k0 += 32) {
        __syncthreads();                 // prior ds_reads done before overwrite
        gload16(pa0 + k0, lA0);
        gload16(pa1 + k0, lA1);
        gload16(pb0 + k0, lB0);
        gload16(pb1 + k0, lB1);
        __syncthreads();                 // loads landed (vmcnt drained at barrier)

        short8 af[4], bf[4];
#pragma unroll
        for (int mi = 0; mi < 4; ++mi)
            af[mi] = *(const short8*)&As[(wm + mi * 16 + lr) * 32 + lq * 8];
#pragma unroll
        for (int ni = 0; ni < 4; ++ni)
            bf[ni] = *(const short8*)&Bs[(wn + ni * 16 + lr) * 32 + lq * 8];
#pragma unroll
        for (int mi = 0; mi < 4; ++mi)
#pragma unroll
            for (int ni = 0; ni < 4; ++ni)
                acc[mi][ni] = __builtin_amdgcn_mfma_f32_16x16x32_bf16(
                    af[mi], bf[ni], acc[mi][ni], 0, 0, 0);
    }

    // epilogue: gelu -> bf16 h
#pragma unroll
    for (int mi = 0; mi < 4; ++mi) {
#pragma unroll
        for (int r = 0; r < 4; ++r) {
            int m = mt * 128 + wm + mi * 16 + lq * 4 + r;
            if (m < cnt) {
                ushort_t* hp = h + (size_t)(base + m) * HFF_DIM + nt * 128 + wn + lr;
#pragma unroll
                for (int ni = 0; ni < 4; ++ni)
                    hp[ni * 16] = f2b(gelu_tanh(acc[mi][ni][r]));
            }
        }
    }
}

// ---------------- GEMM2: out[tok] += gate * (h[row] . W2b[e]^T) ----------------
// R8/R13-verified structure, untouched.
__global__ __launch_bounds__(256) void gemm2_kernel(
        const ushort_t* __restrict__ h, const ushort_t* __restrict__ W2b,
        const int* __restrict__ count, const int* __restrict__ token_id,
        const float* __restrict__ gate, float* __restrict__ out) {
    const int wg  = blockIdx.x;
    const int swz = (wg & 7) * (G2_BLOCKS / 8) + (wg >> 3);
    const int e   = swz >> 8;           // 32 mt * 8 nt = 256 per expert
    const int rem = swz & 255;
    const int mt  = rem >> 3;
    const int nt  = rem & 7;

    const int cnt = count[e];
    if (mt * 128 >= cnt) return;
    int base = 0;
    for (int i = 0; i < e; ++i) base += count[i];

    __shared__ __align__(16) ushort_t As[128 * 32];
    __shared__ __align__(16) ushort_t Bs[128 * 32];

    const int tid = threadIdx.x;
    const int lane = tid & 63;
    const int wave = tid >> 6;

    const int sr0 = (wave << 5) + (lane >> 2);
    const int sr1 = sr0 + 16;
    const int sc  = (lane & 3) << 3;

    int ra0 = mt * 128 + sr0; if (ra0 >= cnt) ra0 = cnt - 1;
    int ra1 = mt * 128 + sr1; if (ra1 >= cnt) ra1 = cnt - 1;
    const ushort_t* pa0 = h + (size_t)(base + ra0) * HFF_DIM + sc;
    const ushort_t* pa1 = h + (size_t)(base + ra1) * HFF_DIM + sc;
    const ushort_t* pb0 = W2b + (size_t)e * H_DIM * HFF_DIM
                          + (size_t)(nt * 128 + sr0) * HFF_DIM + sc;
    const ushort_t* pb1 = pb0 + (size_t)16 * HFF_DIM;
    ushort_t* lA0 = &As[wave << 10];
    ushort_t* lA1 = lA0 + 512;
    ushort_t* lB0 = &Bs[wave << 10];
    ushort_t* lB1 = lB0 + 512;

    const int wm = (wave >> 1) << 6;
    const int wn = (wave & 1) << 6;
    const int lr = lane & 15;
    const int lq = lane >> 4;

    f32x4 acc[4][4];
#pragma unroll
    for (int mi = 0; mi < 4; ++mi)
#pragma unroll
        for (int ni = 0; ni < 4; ++ni)
            acc[mi][ni] = (f32x4){0.f, 0.f, 0.f, 0.f};

    for (int k0 = 0; k0 < HFF_DIM; k0 += 32) {
        __syncthreads();
        gload16(pa0 + k0, lA0);
        gload16(pa1 + k0, lA1);
        gload16(pb0 + k0, lB0);
        gload16(pb1 + k0, lB1);
        __syncthreads();

        short8 af[4], bf[4];
#pragma unroll
        for (int mi = 0; mi < 4; ++mi)
            af[mi] = *(const short8*)&As[(wm + mi * 16 + lr) * 32 + lq * 8];
#pragma unroll
        for (int ni = 0; ni < 4; ++ni)
            bf[ni] = *(const short8*)&Bs[(wn + ni * 16 + lr) * 32 + lq * 8];
#pragma unroll
        for (int mi = 0; mi < 4; ++mi)
#pragma unroll
            for (int ni = 0; ni < 4; ++ni)
                acc[mi][ni] = __builtin_amdgcn_mfma_f32_16x16x32_bf16(
                    af[mi], bf[ni], acc[mi][ni], 0, 0, 0);
    }

    // epilogue: scale by gate, scatter-add into out
#pragma unroll
    for (int mi = 0; mi < 4; ++mi) {
#pragma unroll
        for (int r = 0; r < 4; ++r) {
            int m = mt * 128 + wm + mi * 16 + lq * 4 + r;
            if (m < cnt) {
                int tok = token_id[e * TOKENS + m];
                float g = gate[e * TOKENS + m];
                float* op = out + (size_t)tok * H_DIM + nt * 128 + wn + lr;
#pragma unroll
                for (int ni = 0; ni < 4; ++ni)
                    atomicAdd(&op[ni * 16], g * acc[mi][ni][r]);
            }
        }
    }
}

extern "C" void kernel_launch(void* const* d_in, const int* in_sizes, int n_in,
                              void* d_out, int out_size, void* d_ws, size_t ws_size,
                              hipStream_t stream) {
    const float* x     = (const float*)d_in[0];
    const float* probs = (const float*)d_in[1];
    const int*   idx   = (const int*)d_in[2];
    const float* W1    = (const float*)d_in[3];
    const float* W2    = (const float*)d_in[4];
    float* out = (float*)d_out;

    char* ws = (char*)d_ws;
    int*      count    = (int*)ws;                               // 8 ints
    int*      token_id = (int*)(ws + 4096);                      // 8*4096 ints (128 KB)
    float*    gate     = (float*)(ws + 4096 + 8 * TOKENS * 4);   // 128 KB
    ushort_t* xb       = (ushort_t*)(ws + ((size_t)1 << 20));    // 8 MB
    ushort_t* W1b      = (ushort_t*)(ws + ((size_t)9 << 20));    // 64 MB

    // overlap path needs W1b + W2b live simultaneously (201 MB total);
    // fall back to R13's shared-buffer serial layout if workspace is smaller.
    const bool overlap = ws_size >= ((size_t)201 << 20);
    ushort_t* W2b = overlap ? (ushort_t*)(ws + ((size_t)73 << 20)) : W1b;
    ushort_t* h   = overlap ? (ushort_t*)(ws + ((size_t)137 << 20))
                            : (ushort_t*)(ws + ((size_t)73 << 20));

    hipMemsetAsync(count, 0, 64, stream);
    hipMemsetAsync(out, 0, (size_t)out_size * sizeof(float), stream);

    // x-cvt + routing + W1-cvt, one BW-bound launch
    prep_kernel<<<XCVT_BLOCKS + W1CVT_BLOCKS, 256, 0, stream>>>(
        probs, idx, x, xb, W1, W1b, count, token_id, gate);

    if (overlap) {
        // gemm1 with W2-cvt filler blocks hiding under its idle capacity
        gemm1_kernel<<<G1_BLOCKS + W2CVT_BLOCKS, 256, 0, stream>>>(
            xb, W1b, count, token_id, h, W2, W2b);
    } else {
        gemm1_kernel<<<G1_BLOCKS, 256, 0, stream>>>(
            xb, W1b, count, token_id, h, W2, W2b);   // no cvt blocks
        int n8 = NEXP * H_DIM * HFF_DIM / 8;
        cvt_kernel<<<(n8 + 255) / 256, 256, 0, stream>>>(W2, W2b, n8);
    }

    gemm2_kernel<<<G2_BLOCKS, 256, 0, stream>>>(h, W2b, count, token_id, gate, out);
}